// Round 2
// baseline (677.770 us; speedup 1.0000x reference)
//
#include <hip/hip_runtime.h>

#define DI __device__ __forceinline__

DI float fsig(float v)  { return 1.0f / (1.0f + __expf(-v)); }
DI float ftanh(float v) { return 1.0f - 2.0f / (__expf(2.0f * v) + 1.0f); }

// ===================== K1: self (spatial) attention =====================
// sa[b,t,n] = sigmoid( tanh(x[b,t,:]@Wg.T + bg) @ Wa.T + ba )[n] * x[b,t,n]
__global__ __launch_bounds__(256)
void k1_selfatt(const float* __restrict__ x,   // [128][128][32]
                const float* __restrict__ Wg,  // [128][32]
                const float* __restrict__ bg,  // [128]
                const float* __restrict__ Wa,  // [32][128]
                const float* __restrict__ ba,  // [32]
                float* __restrict__ sa)        // [128][128][32]
{
    __shared__ float xl[128 * 33];   // [t][n] padded (+1 col of 4B-groups breaks 32-bank stride)
    __shared__ float Wgl[128 * 33];  // [m][n] padded
    __shared__ float WaT[128 * 33];  // [m][n] transposed+padded
    __shared__ float bgl[128];
    __shared__ float bal[32];
    __shared__ float gl[2][128];
    __shared__ float pp[2][4][32];

    const int tid = threadIdx.x;
    const int b = blockIdx.x;

    for (int i = tid; i < 4096; i += 256) {
        int r = i >> 5, n = i & 31;
        xl[r * 33 + n]  = x[b * 4096 + i];
        Wgl[r * 33 + n] = Wg[i];
        int n2 = i >> 7, m2 = i & 127;
        WaT[m2 * 33 + n2] = Wa[i];
    }
    if (tid < 128) bgl[tid] = bg[tid];
    if (tid < 32)  bal[tid] = ba[tid];
    __syncthreads();

    const int tl = tid >> 7;  // 0/1 : two time steps per iteration
    for (int it = 0; it < 64; ++it) {
        {   // g[m] = tanh(x_t . Wg[m] + bg[m])
            const int m = tid & 127;
            const int t = it * 2 + tl;
            float acc = bgl[m];
            #pragma unroll
            for (int n = 0; n < 32; ++n) acc += xl[t * 33 + n] * Wgl[m * 33 + n];
            gl[tl][m] = ftanh(acc);
        }
        __syncthreads();
        {   // pp[tl][c][n] = sum_{m in 32-chunk c} g[m] * Wa[n][m]
            const int n = tid & 31, c = (tid >> 5) & 3;
            float acc = 0.f;
            #pragma unroll
            for (int j = 0; j < 32; ++j) {
                int m = c * 32 + j;
                acc += gl[tl][m] * WaT[m * 33 + n];
            }
            pp[tl][c][n] = acc;
        }
        __syncthreads();
        if (tid < 64) {
            const int tl2 = tid >> 5, n = tid & 31;
            const int t = it * 2 + tl2;
            float s = pp[tl2][0][n] + pp[tl2][1][n] + pp[tl2][2][n] + pp[tl2][3][n] + bal[n];
            sa[b * 4096 + t * 32 + n] = fsig(s) * xl[t * 33 + n];
        }
        __syncthreads();
    }
}

// ===================== shared LSTM scan (weights register-resident) =====================
// 512 threads; thread tid owns gate row j=tid: Wih[j][32] + Whh[j][128] in VGPRs.
// Gate order i,f,g,o (PyTorch). MODE 0: record pre-step (h|c) per t. MODE 1: write h to outp.
template <int MODE>
DI void lstm_scan(const float* __restrict__ xin,  // [128][32] input sequence for this b
                  const float* __restrict__ Wih,  // [512][32]
                  const float* __restrict__ Whh,  // [512][128]
                  const float* __restrict__ bih,
                  const float* __restrict__ bhh,
                  float* __restrict__ rec,        // MODE 0: [128][256]
                  float* __restrict__ outp,       // MODE 1: out + b*32768 + col base, stride 256
                  float* lds)
{
    const int tid = threadIdx.x;   // 512
    float* xl  = lds;              // 4096
    float* h   = lds + 4096;       // 128
    float* c   = lds + 4224;       // 128
    float* act = lds + 4352;       // 512

    for (int i = tid; i < 4096; i += 512) xl[i] = xin[i];
    if (tid < 128) { h[tid] = 0.f; c[tid] = 0.f; }

    float4 wi[8], wh[32];
    {
        const float4* p = (const float4*)(Wih + tid * 32);
        #pragma unroll
        for (int i = 0; i < 8; ++i) wi[i] = p[i];
        const float4* q2 = (const float4*)(Whh + tid * 128);
        #pragma unroll
        for (int i = 0; i < 32; ++i) wh[i] = q2[i];
    }
    const float bias = bih[tid] + bhh[tid];
    const int gate = tid >> 7;
    __syncthreads();

    for (int t = 0; t < 128; ++t) {
        if (MODE == 0) {
            if (tid < 256) rec[t * 256 + tid] = (tid < 128) ? h[tid] : c[tid - 128];
        }
        float acc = bias;
        const float4* x4 = (const float4*)(xl + t * 32);
        #pragma unroll
        for (int i = 0; i < 8; ++i) {
            float4 v = x4[i];
            acc += wi[i].x * v.x + wi[i].y * v.y + wi[i].z * v.z + wi[i].w * v.w;
        }
        const float4* h4 = (const float4*)h;
        #pragma unroll
        for (int i = 0; i < 32; ++i) {
            float4 v = h4[i];
            acc += wh[i].x * v.x + wh[i].y * v.y + wh[i].z * v.z + wh[i].w * v.w;
        }
        float a = (gate == 2) ? ftanh(acc) : fsig(acc);
        act[tid] = a;
        __syncthreads();
        if (tid < 128) {
            float iv = act[tid], fv = act[128 + tid], gv = act[256 + tid], ov = act[384 + tid];
            float cn = fv * c[tid] + iv * gv;
            float hn = ov * ftanh(cn);
            c[tid] = cn; h[tid] = hn;
            if (MODE == 1) outp[t * 256 + tid] = hn;
        }
        __syncthreads();
    }
}

// K2: blocks 0..127 -> LSTM0 (record states); blocks 128..255 -> LSTM2 (out cols 128..255)
__global__ __launch_bounds__(512)
void k2_lstm02(const float* __restrict__ x, const float* __restrict__ sa,
               const float* __restrict__ Wih0, const float* __restrict__ Whh0,
               const float* __restrict__ bih0, const float* __restrict__ bhh0,
               const float* __restrict__ Wih2, const float* __restrict__ Whh2,
               const float* __restrict__ bih2, const float* __restrict__ bhh2,
               float* __restrict__ rec, float* __restrict__ out)
{
    __shared__ float lds[4864];
    const int blk = blockIdx.x;
    if (blk < 128) {
        lstm_scan<0>(x + blk * 4096, Wih0, Whh0, bih0, bhh0,
                     rec + blk * 32768, nullptr, lds);
    } else {
        const int b = blk - 128;
        lstm_scan<1>(sa + b * 4096, Wih2, Whh2, bih2, bhh2,
                     nullptr, out + b * 32768 + 128, lds);
    }
}

// K4: LSTM1 over input_attention -> out cols 0..127
__global__ __launch_bounds__(512)
void k4_lstm1(const float* __restrict__ ia,
              const float* __restrict__ Wih1, const float* __restrict__ Whh1,
              const float* __restrict__ bih1, const float* __restrict__ bhh1,
              float* __restrict__ out)
{
    __shared__ float lds[4864];
    const int b = blockIdx.x;
    lstm_scan<1>(ia + b * 4096, Wih1, Whh1, bih1, bhh1, nullptr, out + b * 32768, lds);
}

// ===================== K3: input attention, fully parallel over (b, t-chunk) =====================
// block = (b, 32-t chunk); 512 threads = (ta = tid&127, q = tid>>7)
__global__ __launch_bounds__(512)
void k3_attn(const float* __restrict__ x,    // [128][128][32]
             const float* __restrict__ Ue,   // [128][32]
             const float* __restrict__ We,   // [128][256]
             const float* __restrict__ Ve,   // [128]
             const float* __restrict__ rec,  // [B][T][256] = (h|c) pre-step states
             float* __restrict__ ia)         // [128][128][32]
{
    __shared__ float uxl[128 * 128];  // [m][tau]  (build/read both have tau lane-consecutive: conflict-free)
    __shared__ float xl[128 * 33];    // [tau][n] padded
    __shared__ float Uel[128 * 32];
    __shared__ float hs[256];
    __shared__ float wv[128];
    __shared__ float ep[4][128];
    __shared__ float ev[128];
    __shared__ float av[128];
    __shared__ float iap[16][32];
    __shared__ float red[2];

    const int tid = threadIdx.x;      // 512
    const int b  = blockIdx.x >> 2;
    const int tc = blockIdx.x & 3;

    for (int i = tid; i < 4096; i += 512) {
        xl[(i >> 5) * 33 + (i & 31)] = x[b * 4096 + i];
        Uel[i] = Ue[i];
    }
    __syncthreads();

    const int ta = tid & 127;
    const int q  = tid >> 7;

    // build uxl[m][tau] = sum_n x[tau][n]*Ue[m][n]; thread owns tau=ta, covers m in [32q,32q+32)
    {
        float xr[32];
        #pragma unroll
        for (int n = 0; n < 32; ++n) xr[n] = xl[ta * 33 + n];
        for (int mj = 0; mj < 32; ++mj) {
            const int m = q * 32 + mj;
            const float4* u4 = (const float4*)(Uel + m * 32);
            float acc = 0.f;
            #pragma unroll
            for (int i = 0; i < 8; ++i) {
                float4 v = u4[i];
                acc += xr[4*i] * v.x + xr[4*i+1] * v.y + xr[4*i+2] * v.z + xr[4*i+3] * v.w;
            }
            uxl[m * 128 + ta] = acc;
        }
    }

    // We row m=ta, k in [64q,64q+64) -> registers
    float4 wer[16];
    {
        const float4* p = (const float4*)(We + ta * 256 + q * 64);
        #pragma unroll
        for (int i = 0; i < 16; ++i) wer[i] = p[i];
    }
    float ver[32];
    #pragma unroll
    for (int j = 0; j < 32; ++j) ver[j] = Ve[q * 32 + j];
    __syncthreads();

    for (int tl = 0; tl < 32; ++tl) {
        const int t = tc * 32 + tl;
        if (tid < 256) hs[tid] = rec[(b * 128 + t) * 256 + tid];
        __syncthreads();
        {   // w partial over k-quarter
            const float4* h4 = (const float4*)(hs + q * 64);
            float acc = 0.f;
            #pragma unroll
            for (int i = 0; i < 16; ++i) {
                float4 v = h4[i];
                acc += wer[i].x * v.x + wer[i].y * v.y + wer[i].z * v.z + wer[i].w * v.w;
            }
            ep[q][ta] = acc;
        }
        __syncthreads();
        if (tid < 128) wv[tid] = ep[0][tid] + ep[1][tid] + ep[2][tid] + ep[3][tid];
        __syncthreads();
        {   // e partial: tau=ta, m in [32q,32q+32)
            float wreg[32];
            const float4* w4 = (const float4*)(wv + q * 32);
            #pragma unroll
            for (int i = 0; i < 8; ++i) {
                float4 v = w4[i];
                wreg[4*i] = v.x; wreg[4*i+1] = v.y; wreg[4*i+2] = v.z; wreg[4*i+3] = v.w;
            }
            float acc = 0.f;
            #pragma unroll
            for (int j = 0; j < 32; ++j) {
                const int m = q * 32 + j;
                acc += ver[j] * ftanh(uxl[m * 128 + ta] + wreg[j]);
            }
            ep[q][ta] = acc;
        }
        __syncthreads();
        if (tid < 128) ev[tid] = ep[0][tid] + ep[1][tid] + ep[2][tid] + ep[3][tid];
        __syncthreads();
        if (tid < 64) {
            float m2 = fmaxf(ev[tid], ev[tid + 64]);
            #pragma unroll
            for (int o = 32; o > 0; o >>= 1) m2 = fmaxf(m2, __shfl_xor(m2, o));
            if (tid == 0) red[0] = m2;
        }
        __syncthreads();
        if (tid < 128) av[tid] = __expf(ev[tid] - red[0]);
        __syncthreads();
        if (tid < 64) {
            float s = av[tid] + av[tid + 64];
            #pragma unroll
            for (int o = 32; o > 0; o >>= 1) s += __shfl_xor(s, o);
            if (tid == 0) red[1] = 1.f / s;
        }
        __syncthreads();
        {   // ia partial: n = tid&31, 8 taus per group
            const int n = tid & 31, g = tid >> 5;
            float acc = 0.f;
            #pragma unroll
            for (int j = 0; j < 8; ++j) {
                const int t2 = g * 8 + j;
                acc += av[t2] * xl[t2 * 33 + n];
            }
            iap[g][n] = acc;
        }
        __syncthreads();
        if (tid < 32) {
            float s = 0.f;
            #pragma unroll
            for (int g = 0; g < 16; ++g) s += iap[g][tid];
            ia[(b * 128 + t) * 32 + tid] = s * red[1];
        }
        __syncthreads();
    }
}

extern "C" void kernel_launch(void* const* d_in, const int* in_sizes, int n_in,
                              void* d_out, int out_size, void* d_ws, size_t ws_size,
                              hipStream_t stream)
{
    const float* x    = (const float*)d_in[0];
    const float* Wih0 = (const float*)d_in[1];
    const float* Whh0 = (const float*)d_in[2];
    const float* bih0 = (const float*)d_in[3];
    const float* bhh0 = (const float*)d_in[4];
    const float* We   = (const float*)d_in[5];
    const float* Ue   = (const float*)d_in[6];
    const float* Ve   = (const float*)d_in[7];
    const float* Wg   = (const float*)d_in[8];
    const float* bg   = (const float*)d_in[9];
    const float* Wa   = (const float*)d_in[10];
    const float* ba   = (const float*)d_in[11];
    const float* Wih1 = (const float*)d_in[12];
    const float* Whh1 = (const float*)d_in[13];
    const float* bih1 = (const float*)d_in[14];
    const float* bhh1 = (const float*)d_in[15];
    const float* Wih2 = (const float*)d_in[16];
    const float* Whh2 = (const float*)d_in[17];
    const float* bih2 = (const float*)d_in[18];
    const float* bhh2 = (const float*)d_in[19];

    float* out = (float*)d_out;
    float* ws  = (float*)d_ws;
    // workspace layout (floats): sa 524288 | rec 4194304 | ia 524288  => 20 MiB total
    float* sa  = ws;
    float* rec = ws + 524288;
    float* iaw = ws + 4718592;

    k1_selfatt<<<128, 256, 0, stream>>>(x, Wg, bg, Wa, ba, sa);
    k2_lstm02<<<256, 512, 0, stream>>>(x, sa, Wih0, Whh0, bih0, bhh0,
                                       Wih2, Whh2, bih2, bhh2, rec, out);
    k3_attn<<<512, 512, 0, stream>>>(x, Ue, We, Ve, rec, iaw);
    k4_lstm1<<<128, 512, 0, stream>>>(iaw, Wih1, Whh1, bih1, bhh1, out);
}

// Round 3
// 528.890 us; speedup vs baseline: 1.2815x; 1.2815x over previous
//
#include <hip/hip_runtime.h>

#define DI __device__ __forceinline__

DI float fsig(float v)  { return 1.0f / (1.0f + __expf(-v)); }
DI float ftanh(float v) { return 1.0f - 2.0f / (__expf(2.0f * v) + 1.0f); }

// ===================== shared LSTM scan (weights register-resident) =====================
// 512 threads; thread tid owns gate row j=tid: Wih[j][32] + Whh[j][128] in VGPRs.
// MODE 0: record pre-step (h|c) per t. MODE 1: write h to outp (stride 256).
template <int MODE>
DI void lstm_scan(const float* __restrict__ xin,  // [128][32]
                  const float* __restrict__ Wih,  // [512][32]
                  const float* __restrict__ Whh,  // [512][128]
                  const float* __restrict__ bih,
                  const float* __restrict__ bhh,
                  float* __restrict__ rec,        // MODE 0: [128][256]
                  float* __restrict__ outp,       // MODE 1
                  float* lds)
{
    const int tid = threadIdx.x;   // 512
    float* xl  = lds;              // 4096
    float* h   = lds + 4096;       // 128
    float* c   = lds + 4224;       // 128
    float* act = lds + 4352;       // 512

    for (int i = tid; i < 4096; i += 512) xl[i] = xin[i];
    if (tid < 128) { h[tid] = 0.f; c[tid] = 0.f; }

    float4 wi[8], wh[32];
    {
        const float4* p = (const float4*)(Wih + tid * 32);
        #pragma unroll
        for (int i = 0; i < 8; ++i) wi[i] = p[i];
        const float4* q2 = (const float4*)(Whh + tid * 128);
        #pragma unroll
        for (int i = 0; i < 32; ++i) wh[i] = q2[i];
    }
    const float bias = bih[tid] + bhh[tid];
    const int gate = tid >> 7;
    __syncthreads();

    for (int t = 0; t < 128; ++t) {
        if (MODE == 0) {
            if (tid < 256) rec[t * 256 + tid] = (tid < 128) ? h[tid] : c[tid - 128];
        }
        float acc = bias;
        const float4* x4 = (const float4*)(xl + t * 32);
        #pragma unroll
        for (int i = 0; i < 8; ++i) {
            float4 v = x4[i];
            acc += wi[i].x * v.x + wi[i].y * v.y + wi[i].z * v.z + wi[i].w * v.w;
        }
        const float4* h4 = (const float4*)h;
        #pragma unroll
        for (int i = 0; i < 32; ++i) {
            float4 v = h4[i];
            acc += wh[i].x * v.x + wh[i].y * v.y + wh[i].z * v.z + wh[i].w * v.w;
        }
        float a = (gate == 2) ? ftanh(acc) : fsig(acc);
        act[tid] = a;
        __syncthreads();
        if (tid < 128) {
            float iv = act[tid], fv = act[128 + tid], gv = act[256 + tid], ov = act[384 + tid];
            float cn = fv * c[tid] + iv * gv;
            float hn = ov * ftanh(cn);
            c[tid] = cn; h[tid] = hn;
            if (MODE == 1) outp[t * 256 + tid] = hn;
        }
        __syncthreads();
    }
}

// self-attention (512-thread variant), 4 time steps per iteration
DI void selfatt_body(const float* __restrict__ x, const float* __restrict__ Wg,
                     const float* __restrict__ bg, const float* __restrict__ Wa,
                     const float* __restrict__ ba, float* __restrict__ sa,
                     int b, float* s)
{
    float* xl  = s;                // 128*33
    float* Wgl = s + 4224;
    float* WaT = s + 8448;
    float* bgl = s + 12672;        // 128
    float* bal = s + 12800;        // 32
    float* gl  = s + 12832;        // 4*128
    float* pp  = s + 13344;        // 4*4*32

    const int tid = threadIdx.x;
    for (int i = tid; i < 4096; i += 512) {
        int r = i >> 5, n = i & 31;
        xl[r * 33 + n]  = x[b * 4096 + i];
        Wgl[r * 33 + n] = Wg[i];
        WaT[(i & 127) * 33 + (i >> 7)] = Wa[i];
    }
    if (tid < 128) bgl[tid] = bg[tid];
    else if (tid < 160) bal[tid - 128] = ba[tid - 128];
    __syncthreads();

    const int tl = tid >> 7;          // 0..3
    for (int it = 0; it < 32; ++it) {
        {   const int m = tid & 127;
            const int t = it * 4 + tl;
            float acc = bgl[m];
            #pragma unroll
            for (int n = 0; n < 32; ++n) acc += xl[t * 33 + n] * Wgl[m * 33 + n];
            gl[tl * 128 + m] = ftanh(acc);
        }
        __syncthreads();
        {   const int n = tid & 31, c = (tid >> 5) & 3;
            float acc = 0.f;
            #pragma unroll
            for (int j = 0; j < 32; ++j) {
                int m = c * 32 + j;
                acc += gl[tl * 128 + m] * WaT[m * 33 + n];
            }
            pp[(tl * 4 + c) * 32 + n] = acc;
        }
        __syncthreads();
        if (tid < 128) {
            const int tl2 = tid >> 5, n = tid & 31;
            const int t = it * 4 + tl2;
            float sv = pp[(tl2 * 4 + 0) * 32 + n] + pp[(tl2 * 4 + 1) * 32 + n]
                     + pp[(tl2 * 4 + 2) * 32 + n] + pp[(tl2 * 4 + 3) * 32 + n] + bal[n];
            sa[b * 4096 + t * 32 + n] = fsig(sv) * xl[t * 33 + n];
        }
        __syncthreads();
    }
}

// kA: blocks 0..127 -> LSTM0 (record rec); blocks 128..255 -> self-attention (sa)
__global__ __launch_bounds__(512)
void kA_lstm0_sa(const float* __restrict__ x,
                 const float* __restrict__ Wih0, const float* __restrict__ Whh0,
                 const float* __restrict__ bih0, const float* __restrict__ bhh0,
                 const float* __restrict__ Wg, const float* __restrict__ bg,
                 const float* __restrict__ Wa, const float* __restrict__ ba,
                 float* __restrict__ rec, float* __restrict__ sa)
{
    __shared__ float smem[13856];
    const int blk = blockIdx.x;
    if (blk < 128) {
        lstm_scan<0>(x + blk * 4096, Wih0, Whh0, bih0, bhh0,
                     rec + blk * 32768, nullptr, smem);
    } else {
        selfatt_body(x, Wg, bg, Wa, ba, sa, blk - 128, smem);
    }
}

// kC: blocks 0..127 -> LSTM1 (ia -> out cols 0..127); 128..255 -> LSTM2 (sa -> cols 128..255)
__global__ __launch_bounds__(512)
void kC_lstm12(const float* __restrict__ ia, const float* __restrict__ sa,
               const float* __restrict__ Wih1, const float* __restrict__ Whh1,
               const float* __restrict__ bih1, const float* __restrict__ bhh1,
               const float* __restrict__ Wih2, const float* __restrict__ Whh2,
               const float* __restrict__ bih2, const float* __restrict__ bhh2,
               float* __restrict__ out)
{
    __shared__ float smem[4864];
    const int blk = blockIdx.x;
    if (blk < 128) {
        lstm_scan<1>(ia + blk * 4096, Wih1, Whh1, bih1, bhh1,
                     nullptr, out + blk * 32768, smem);
    } else {
        const int b = blk - 128;
        lstm_scan<1>(sa + b * 4096, Wih2, Whh2, bih2, bhh2,
                     nullptr, out + b * 32768 + 128, smem);
    }
}

// ===================== kB: input attention =====================
// block = (b, 32-t chunk); 512 threads: ta = tid>>2 (tau / m-row), q = tid&3.
// ux kept in registers (uxr[j] = 2*ux[m=4j+q][ta]); W precomputed per chunk into wl.
__global__ __launch_bounds__(512, 4)
void kB_attn(const float* __restrict__ x,    // [128][128][32]
             const float* __restrict__ Ue,   // [128][32]
             const float* __restrict__ We,   // [128][256]
             const float* __restrict__ Ve,   // [128]
             const float* __restrict__ rec,  // [B][T][256] pre-step (h|c)
             float* __restrict__ ia)         // [128][128][32]
{
    __shared__ float xl[4608];     // [tau][36] padded
    __shared__ float wl[4608];     // [32 t][4 q][36] padded, pre-scaled by 2
    __shared__ float ubuf[4608];   // union: hsp [16][272] then Uel [128][36]
    __shared__ float ev[128];
    __shared__ float av[128];
    __shared__ float iap[576];     // [16][36]
    __shared__ float wred[2];
    __shared__ float wsum[2];

    const int tid = threadIdx.x;
    const int b  = blockIdx.x >> 2;
    const int tc = blockIdx.x & 3;
    const int ta = tid >> 2;       // 0..127
    const int q  = tid & 3;

    // We row ta, k-quarter q -> registers (flat offset = tid*64, fully coalesced)
    float4 wer[16];
    {
        const float4* p = (const float4*)(We + tid * 64);
        #pragma unroll
        for (int i = 0; i < 16; ++i) wer[i] = p[i];
    }
    for (int i = tid; i < 4096; i += 512)
        xl[(i >> 5) * 36 + (i & 31)] = x[b * 4096 + i];

    // ---- build wl[t][.] = 2 * (We @ [h;c])(t) for the 32 t of this chunk, 16 t per half ----
    const long rbase = (long)b * 32768 + (long)tc * 32 * 256;
    for (int h2 = 0; h2 < 2; ++h2) {
        __syncthreads();
        #pragma unroll
        for (int s = 0; s < 8; ++s) {
            int f = tid + 512 * s;             // 0..4095
            int tl = f >> 8, k = f & 255;
            ubuf[tl * 272 + (k >> 6) * 68 + (k & 63)] =
                rec[rbase + (h2 * 16 + tl) * 256 + k];
        }
        __syncthreads();
        for (int tl = 0; tl < 16; ++tl) {
            const float4* hp = (const float4*)(ubuf + tl * 272 + q * 68);
            float acc = 0.f;
            #pragma unroll
            for (int i = 0; i < 16; ++i) {
                float4 v = hp[i];
                acc += wer[i].x * v.x + wer[i].y * v.y + wer[i].z * v.z + wer[i].w * v.w;
            }
            acc += __shfl_xor(acc, 1);
            acc += __shfl_xor(acc, 2);
            if (q == 0)
                wl[(h2 * 16 + tl) * 144 + (ta & 3) * 36 + (ta >> 2)] = 2.0f * acc;
        }
    }
    __syncthreads();

    // ---- Uel into ubuf, then uxr[j] = 2 * sum_n x[ta][n]*Ue[4j+q][n] ----
    for (int i = tid; i < 4096; i += 512)
        ubuf[(i >> 5) * 36 + (i & 31)] = Ue[i];
    __syncthreads();

    float uxr[32];
    {
        float xr[32];
        const float4* xp = (const float4*)(xl + ta * 36);
        #pragma unroll
        for (int i = 0; i < 8; ++i) {
            float4 v = xp[i];
            xr[4*i] = v.x; xr[4*i+1] = v.y; xr[4*i+2] = v.z; xr[4*i+3] = v.w;
        }
        #pragma unroll
        for (int j = 0; j < 32; ++j) {
            const float4* up = (const float4*)(ubuf + (4 * j + q) * 36);
            float acc = 0.f;
            #pragma unroll
            for (int i = 0; i < 8; ++i) {
                float4 v = up[i];
                acc += xr[4*i] * v.x + xr[4*i+1] * v.y + xr[4*i+2] * v.z + xr[4*i+3] * v.w;
            }
            uxr[j] = 2.0f * acc;
        }
    }

    float ver[32];
    #pragma unroll
    for (int j = 0; j < 32; ++j) ver[j] = Ve[4 * j + q];
    float VeTot;
    {
        float vs = 0.f;
        #pragma unroll
        for (int j = 0; j < 32; ++j) vs += ver[j];
        vs += __shfl_xor(vs, 1);
        vs += __shfl_xor(vs, 2);
        VeTot = vs;
    }

    // ---- main loop over the 32 t of this chunk ----
    for (int tl = 0; tl < 32; ++tl) {
        const int t = tc * 32 + tl;
        // e-partial: sum_m Ve[m]*tanh(z), tanh(z) = 1 - 2/(exp(2z)+1); uxr/wl hold 2z parts
        float acc2 = 0.f;
        const float4* wr = (const float4*)(wl + tl * 144 + q * 36);
        #pragma unroll
        for (int j4 = 0; j4 < 8; ++j4) {
            float4 w4 = wr[j4];
            {   float zs = uxr[4*j4+0] + w4.x;
                acc2 += ver[4*j4+0] * __fdividef(2.0f, __expf(zs) + 1.0f); }
            {   float zs = uxr[4*j4+1] + w4.y;
                acc2 += ver[4*j4+1] * __fdividef(2.0f, __expf(zs) + 1.0f); }
            {   float zs = uxr[4*j4+2] + w4.z;
                acc2 += ver[4*j4+2] * __fdividef(2.0f, __expf(zs) + 1.0f); }
            {   float zs = uxr[4*j4+3] + w4.w;
                acc2 += ver[4*j4+3] * __fdividef(2.0f, __expf(zs) + 1.0f); }
        }
        acc2 += __shfl_xor(acc2, 1);
        acc2 += __shfl_xor(acc2, 2);
        if (q == 0) ev[ta] = VeTot - acc2;
        __syncthreads();                       // B1

        float vv = 0.f, aa;
        if (tid < 128) {
            vv = ev[tid];
            float m2 = vv;
            #pragma unroll
            for (int o = 32; o > 0; o >>= 1) m2 = fmaxf(m2, __shfl_xor(m2, o));
            if ((tid & 63) == 0) wred[tid >> 6] = m2;
        }
        __syncthreads();                       // B2
        if (tid < 128) {
            float M = fmaxf(wred[0], wred[1]);
            aa = __expf(vv - M);
            av[tid] = aa;
            float s = aa;
            #pragma unroll
            for (int o = 32; o > 0; o >>= 1) s += __shfl_xor(s, o);
            if ((tid & 63) == 0) wsum[tid >> 6] = s;
        }
        __syncthreads();                       // B3
        {   const int n = tid & 31, g = tid >> 5;
            float accp = 0.f;
            #pragma unroll
            for (int jj = 0; jj < 8; ++jj) {
                const int t2 = g * 8 + jj;
                accp += av[t2] * xl[t2 * 36 + n];
            }
            iap[g * 36 + n] = accp;
        }
        __syncthreads();                       // B4
        if (tid < 32) {
            float s = 0.f;
            #pragma unroll
            for (int g = 0; g < 16; ++g) s += iap[g * 36 + tid];
            float scale = __fdividef(1.0f, wsum[0] + wsum[1]);
            ia[((long)b * 128 + t) * 32 + tid] = s * scale;
        }
    }
}

extern "C" void kernel_launch(void* const* d_in, const int* in_sizes, int n_in,
                              void* d_out, int out_size, void* d_ws, size_t ws_size,
                              hipStream_t stream)
{
    const float* x    = (const float*)d_in[0];
    const float* Wih0 = (const float*)d_in[1];
    const float* Whh0 = (const float*)d_in[2];
    const float* bih0 = (const float*)d_in[3];
    const float* bhh0 = (const float*)d_in[4];
    const float* We   = (const float*)d_in[5];
    const float* Ue   = (const float*)d_in[6];
    const float* Ve   = (const float*)d_in[7];
    const float* Wg   = (const float*)d_in[8];
    const float* bg   = (const float*)d_in[9];
    const float* Wa   = (const float*)d_in[10];
    const float* ba   = (const float*)d_in[11];
    const float* Wih1 = (const float*)d_in[12];
    const float* Whh1 = (const float*)d_in[13];
    const float* bih1 = (const float*)d_in[14];
    const float* bhh1 = (const float*)d_in[15];
    const float* Wih2 = (const float*)d_in[16];
    const float* Whh2 = (const float*)d_in[17];
    const float* bih2 = (const float*)d_in[18];
    const float* bhh2 = (const float*)d_in[19];

    float* out = (float*)d_out;
    float* ws  = (float*)d_ws;
    // workspace (floats): sa 524288 | rec 4194304 | ia 524288
    float* sa  = ws;
    float* rec = ws + 524288;
    float* iaw = ws + 4718592;

    kA_lstm0_sa<<<256, 512, 0, stream>>>(x, Wih0, Whh0, bih0, bhh0,
                                         Wg, bg, Wa, ba, rec, sa);
    kB_attn<<<512, 512, 0, stream>>>(x, Ue, We, Ve, rec, iaw);
    kC_lstm12<<<256, 512, 0, stream>>>(iaw, sa, Wih1, Whh1, bih1, bhh1,
                                       Wih2, Whh2, bih2, bhh2, out);
}